// Round 1
// baseline (791.858 us; speedup 1.0000x reference)
//
#include <hip/hip_runtime.h>

#define N 8000
#define NP 8064      // padded stride (63 tiles of 128)
#define C 96
#define OCH 19
#define NT 63        // number of 128-wide tiles covering 8064
#define JC 9         // chunks for deterministic two-stage reductions
#define TPC 7        // tiles per chunk (JC*TPC == NT)
#define U1 (1.0f/8000.0f)

// ---------------- small setup kernels ----------------

// diff = inv(posses[1]) @ posses[0], computed in f64 Gauss-Jordan, stored f32
__global__ void k_diff(const float* __restrict__ posses, float* __restrict__ diff) {
    if (threadIdx.x != 0 || blockIdx.x != 0) return;
    double M[4][8];
    for (int r = 0; r < 4; ++r)
        for (int c = 0; c < 4; ++c) {
            M[r][c] = (double)posses[16 + r*4 + c];
            M[r][4+c] = (r == c) ? 1.0 : 0.0;
        }
    for (int col = 0; col < 4; ++col) {
        int piv = col; double best = fabs(M[col][col]);
        for (int r = col+1; r < 4; ++r) { double v = fabs(M[r][col]); if (v > best) { best = v; piv = r; } }
        if (piv != col) for (int c = 0; c < 8; ++c) { double t = M[col][c]; M[col][c] = M[piv][c]; M[piv][c] = t; }
        double inv = 1.0 / M[col][col];
        for (int c = 0; c < 8; ++c) M[col][c] *= inv;
        for (int r = 0; r < 4; ++r) if (r != col) {
            double f = M[r][col];
            for (int c = 0; c < 8; ++c) M[r][c] -= f * M[col][c];
        }
    }
    for (int r = 0; r < 4; ++r)
        for (int c = 0; c < 4; ++c) {
            double s = 0.0;
            for (int k = 0; k < 4; ++k) s += M[r][4+k] * (double)posses[k*4 + c];
            diff[r*4 + c] = (float)s;
        }
}

// per-row (i side): w1 = ||mean_features||, xn = sum(ori^2), oriT transposed
__global__ void k_prepA(const float* __restrict__ mf, const float* __restrict__ ori,
                        float* __restrict__ w1, float* __restrict__ xn, float* __restrict__ oriT) {
    int i = blockIdx.x * 256 + threadIdx.x;
    if (i >= NP) return;
    if (i < N) {
        float s = 0.f;
        for (int k = 0; k < C; ++k) { float v = mf[i*C + k]; s += v*v; }
        w1[i] = sqrtf(s);
        float c0 = ori[i*3], c1 = ori[i*3+1], c2 = ori[i*3+2];
        xn[i] = c0*c0 + c1*c1 + c2*c2;
        oriT[i] = c0; oriT[NP + i] = c1; oriT[2*NP + i] = c2;
    } else {
        w1[i] = 0.f; xn[i] = 1e30f;          // pad: forces support=0
        oriT[i] = 0.f; oriT[NP + i] = 0.f; oriT[2*NP + i] = 0.f;
    }
}

// per-row (j side): al = (diff @ [c,1])[:3], yn = sum(al^2), w2 = ||sur_feat||
__global__ void k_prepB(const float* __restrict__ sf, const float* __restrict__ coords,
                        const float* __restrict__ diff,
                        float* __restrict__ w2, float* __restrict__ yn, float* __restrict__ alT) {
    int j = blockIdx.x * 256 + threadIdx.x;
    if (j >= NP) return;
    if (j < N) {
        float s = 0.f;
        for (int k = 0; k < C; ++k) { float v = sf[j*C + k]; s += v*v; }
        w2[j] = sqrtf(s);
        float c0 = coords[j*3], c1 = coords[j*3+1], c2 = coords[j*3+2];
        float a0 = (diff[0]*c0 + diff[1]*c1) + (diff[2]*c2 + diff[3]);
        float a1 = (diff[4]*c0 + diff[5]*c1) + (diff[6]*c2 + diff[7]);
        float a2 = (diff[8]*c0 + diff[9]*c1) + (diff[10]*c2 + diff[11]);
        alT[j] = a0; alT[NP + j] = a1; alT[2*NP + j] = a2;
        yn[j] = a0*a0 + a1*a1 + a2*a2;
    } else {
        w2[j] = 0.f; yn[j] = 1e30f;
        alT[j] = 0.f; alT[NP + j] = 0.f; alT[2*NP + j] = 0.f;
    }
}

// transpose [N][96] -> [96][NP] (k-major, zero-padded)
__global__ void k_trans(const float* __restrict__ src, float* __restrict__ dst) {
    int i = blockIdx.x * 256 + threadIdx.x;
    int k4 = blockIdx.y;
    if (i >= NP) return;
    float4 v = make_float4(0.f, 0.f, 0.f, 0.f);
    if (i < N) v = ((const float4*)src)[i*(C/4) + k4];
    dst[(4*k4+0)*NP + i] = v.x;
    dst[(4*k4+1)*NP + i] = v.y;
    dst[(4*k4+2)*NP + i] = v.z;
    dst[(4*k4+3)*NP + i] = v.w;
}

__global__ void k_softmax(const float* __restrict__ p, float* __restrict__ svp) {
    int i = blockIdx.x * 256 + threadIdx.x;
    if (i >= N) return;
    float m = -1e30f;
    for (int c = 0; c < OCH; ++c) m = fmaxf(m, p[i*OCH + c]);
    float e[OCH]; float s = 0.f;
    for (int c = 0; c < OCH; ++c) { e[c] = expf(p[i*OCH + c] - m); s += e[c]; }
    for (int c = 0; c < OCH; ++c) svp[i*OCH + c] = e[c] / s;
}

__global__ void k_init(int* __restrict__ winner, int* __restrict__ flags) {
    int i = blockIdx.x * 256 + threadIdx.x;
    if (i < N) winner[i] = -1;
    if (i == 0) { flags[0] = 0; flags[1] = 0; }
}

// ---------------- main fused GEMM passes ----------------
// K[i,j] = support(i,j) * exp(-(1 + (1 - dot/max(w1*w2,1e-8)) - exp(-0.5*cd)) / 0.03)
// cd = max(xn + yn - 2*<ori_i, al_j>, 0) / 0.25 ; support = cd < 100

__launch_bounds__(256, 1)
__global__ void k_rowsum(const float* __restrict__ At, const float* __restrict__ Bt,
                         const float* __restrict__ oriT, const float* __restrict__ alT,
                         const float* __restrict__ w1, const float* __restrict__ xn,
                         const float* __restrict__ w2, const float* __restrict__ yn,
                         float* __restrict__ rowpart) {
    __shared__ float sA[C*128];
    __shared__ float sB[C*128];
    __shared__ float sAw[256];    // w1 | xn
    __shared__ float sAo[384];    // oriT x3
    __shared__ float sBw[256];    // w2 | yn
    __shared__ float sBa[384];    // alT x3

    int tid = threadIdx.x;
    int tx = tid & 15, ty = tid >> 4;
    int i0 = blockIdx.x * 128;
    int jt0 = blockIdx.y * TPC;

    // stage resident A strip (k-major, coalesced global, contiguous LDS)
    for (int idx = tid; idx < C*32; idx += 256) {
        int k = idx >> 5, i4 = (idx & 31) * 4;
        *(float4*)&sA[k*128 + i4] = *(const float4*)&At[k*NP + i0 + i4];
    }
    if (tid < 128) {
        sAw[tid] = w1[i0 + tid]; sAw[128 + tid] = xn[i0 + tid];
        sAo[tid] = oriT[i0 + tid]; sAo[128 + tid] = oriT[NP + i0 + tid]; sAo[256 + tid] = oriT[2*NP + i0 + tid];
    }

    float racc[8];
    #pragma unroll
    for (int r = 0; r < 8; ++r) racc[r] = 0.f;

    for (int jt = jt0; jt < jt0 + TPC; ++jt) {
        int j0 = jt * 128;
        __syncthreads();
        for (int idx = tid; idx < C*32; idx += 256) {
            int k = idx >> 5, i4 = (idx & 31) * 4;
            *(float4*)&sB[k*128 + i4] = *(const float4*)&Bt[k*NP + j0 + i4];
        }
        if (tid < 128) {
            sBw[tid] = w2[j0 + tid]; sBw[128 + tid] = yn[j0 + tid];
            sBa[tid] = alT[j0 + tid]; sBa[128 + tid] = alT[NP + j0 + tid]; sBa[256 + tid] = alT[2*NP + j0 + tid];
        }
        __syncthreads();

        float acc[8][8];
        #pragma unroll
        for (int r = 0; r < 8; ++r)
            #pragma unroll
            for (int q = 0; q < 8; ++q) acc[r][q] = 0.f;

        #pragma unroll 4
        for (int k = 0; k < C; ++k) {
            float4 a0 = *(const float4*)&sA[k*128 + ty*4];
            float4 a1 = *(const float4*)&sA[k*128 + 64 + ty*4];
            float4 b0 = *(const float4*)&sB[k*128 + tx*4];
            float4 b1 = *(const float4*)&sB[k*128 + 64 + tx*4];
            float av[8] = {a0.x,a0.y,a0.z,a0.w,a1.x,a1.y,a1.z,a1.w};
            float bv[8] = {b0.x,b0.y,b0.z,b0.w,b1.x,b1.y,b1.z,b1.w};
            #pragma unroll
            for (int r = 0; r < 8; ++r)
                #pragma unroll
                for (int q = 0; q < 8; ++q) acc[r][q] += av[r]*bv[q];
        }

        #pragma unroll
        for (int r = 0; r < 8; ++r) {
            int il = (r < 4) ? (ty*4 + r) : (64 + ty*4 + r - 4);
            float w1v = sAw[il], xnv = sAw[128 + il];
            float o0 = sAo[il], o1 = sAo[128 + il], o2 = sAo[256 + il];
            #pragma unroll
            for (int q = 0; q < 8; ++q) {
                int jl = (q < 4) ? (tx*4 + q) : (64 + tx*4 + q - 4);
                float cdot = o0*sBa[jl] + o1*sBa[128 + jl] + o2*sBa[256 + jl];
                float cd = fmaxf(xnv + sBw[128 + jl] - 2.f*cdot, 0.f) / 0.25f;
                if (cd < 100.f) {
                    float fdc = 1.f - acc[r][q] / fmaxf(w1v * sBw[jl], 1e-8f);
                    float dist = (1.f + fdc) - expf(-0.5f * cd);
                    float K = expf(-dist / 0.03f);
                    racc[r] += K * U1;
                }
            }
        }
    }

    __syncthreads();
    float* red = sB;  // reuse as 128x16 reduction scratch
    #pragma unroll
    for (int r = 0; r < 8; ++r) {
        int il = (r < 4) ? (ty*4 + r) : (64 + ty*4 + r - 4);
        red[il*16 + tx] = racc[r];
    }
    __syncthreads();
    if (tid < 128 && i0 + tid < N) {
        float s = 0.f;
        for (int t = 0; t < 16; ++t) s += red[tid*16 + t];
        rowpart[blockIdx.y * N + i0 + tid] = s;
    }
}

__global__ void k_breduce(const float* __restrict__ rowpart, float* __restrict__ b) {
    int i = blockIdx.x * 256 + threadIdx.x;
    if (i >= NP) return;
    if (i < N) {
        float s = 0.f;
        for (int c = 0; c < JC; ++c) s += rowpart[c * N + i];
        b[i] = U1 / (s + 1e-16f);
    } else b[i] = 0.f;
}

__launch_bounds__(256, 1)
__global__ void k_argmax(const float* __restrict__ At, const float* __restrict__ Bt,
                         const float* __restrict__ oriT, const float* __restrict__ alT,
                         const float* __restrict__ w1, const float* __restrict__ xn,
                         const float* __restrict__ w2, const float* __restrict__ yn,
                         const float* __restrict__ bvec,
                         float* __restrict__ pval, int* __restrict__ pidx) {
    __shared__ float sB[C*128];   // resident j-strip features
    __shared__ float sA[C*128];   // per-step i-tile features
    __shared__ float sAw[256];
    __shared__ float sAo[384];
    __shared__ float sBw[256];
    __shared__ float sBa[384];
    __shared__ float sbb[128];

    int tid = threadIdx.x;
    int tx = tid & 15, ty = tid >> 4;
    int j0 = blockIdx.x * 128;
    int it0 = blockIdx.y * TPC;

    for (int idx = tid; idx < C*32; idx += 256) {
        int k = idx >> 5, i4 = (idx & 31) * 4;
        *(float4*)&sB[k*128 + i4] = *(const float4*)&Bt[k*NP + j0 + i4];
    }
    if (tid < 128) {
        sBw[tid] = w2[j0 + tid]; sBw[128 + tid] = yn[j0 + tid];
        sBa[tid] = alT[j0 + tid]; sBa[128 + tid] = alT[NP + j0 + tid]; sBa[256 + tid] = alT[2*NP + j0 + tid];
    }

    float best[8]; int bidx[8];
    #pragma unroll
    for (int q = 0; q < 8; ++q) { best[q] = -1.f; bidx[q] = 0; }

    for (int it = it0; it < it0 + TPC; ++it) {
        int i0 = it * 128;
        __syncthreads();
        for (int idx = tid; idx < C*32; idx += 256) {
            int k = idx >> 5, i4 = (idx & 31) * 4;
            *(float4*)&sA[k*128 + i4] = *(const float4*)&At[k*NP + i0 + i4];
        }
        if (tid < 128) {
            sAw[tid] = w1[i0 + tid]; sAw[128 + tid] = xn[i0 + tid];
            sAo[tid] = oriT[i0 + tid]; sAo[128 + tid] = oriT[NP + i0 + tid]; sAo[256 + tid] = oriT[2*NP + i0 + tid];
            sbb[tid] = bvec[i0 + tid];
        }
        __syncthreads();

        float acc[8][8];
        #pragma unroll
        for (int r = 0; r < 8; ++r)
            #pragma unroll
            for (int q = 0; q < 8; ++q) acc[r][q] = 0.f;

        #pragma unroll 4
        for (int k = 0; k < C; ++k) {
            float4 a0 = *(const float4*)&sA[k*128 + ty*4];
            float4 a1 = *(const float4*)&sA[k*128 + 64 + ty*4];
            float4 b0 = *(const float4*)&sB[k*128 + tx*4];
            float4 b1 = *(const float4*)&sB[k*128 + 64 + tx*4];
            float av[8] = {a0.x,a0.y,a0.z,a0.w,a1.x,a1.y,a1.z,a1.w};
            float bv[8] = {b0.x,b0.y,b0.z,b0.w,b1.x,b1.y,b1.z,b1.w};
            #pragma unroll
            for (int r = 0; r < 8; ++r)
                #pragma unroll
                for (int q = 0; q < 8; ++q) acc[r][q] += av[r]*bv[q];
        }

        // iterate i ascending within thread (r 0..7) to keep first-max semantics
        #pragma unroll
        for (int r = 0; r < 8; ++r) {
            int il = (r < 4) ? (ty*4 + r) : (64 + ty*4 + r - 4);
            float w1v = sAw[il], xnv = sAw[128 + il];
            float o0 = sAo[il], o1 = sAo[128 + il], o2 = sAo[256 + il];
            float bb = sbb[il];
            int gi = i0 + il;
            #pragma unroll
            for (int q = 0; q < 8; ++q) {
                int jl = (q < 4) ? (tx*4 + q) : (64 + tx*4 + q - 4);
                float cdot = o0*sBa[jl] + o1*sBa[128 + jl] + o2*sBa[256 + jl];
                float cd = fmaxf(xnv + sBw[128 + jl] - 2.f*cdot, 0.f) / 0.25f;
                float v = 0.f;
                if (cd < 100.f) {
                    float fdc = 1.f - acc[r][q] / fmaxf(w1v * sBw[jl], 1e-8f);
                    float dist = (1.f + fdc) - expf(-0.5f * cd);
                    v = expf(-dist / 0.03f) * bb;
                }
                if (v > best[q]) { best[q] = v; bidx[q] = gi; }
            }
        }
    }

    __syncthreads();
    float* rv = sA;                    // 128*16 floats
    int* ri = (int*)(sA + 2048);       // 128*16 ints
    #pragma unroll
    for (int q = 0; q < 8; ++q) {
        int jl = (q < 4) ? (tx*4 + q) : (64 + tx*4 + q - 4);
        rv[jl*16 + ty] = best[q];
        ri[jl*16 + ty] = bidx[q];
    }
    __syncthreads();
    if (tid < 128 && j0 + tid < N) {
        float bv = -2.f; int bi = 0;
        for (int t = 0; t < 16; ++t) {
            float v = rv[tid*16 + t]; int id = ri[tid*16 + t];
            if (v > bv || (v == bv && id < bi)) { bv = v; bi = id; }
        }
        pval[blockIdx.y * N + j0 + tid] = bv;
        pidx[blockIdx.y * N + j0 + tid] = bi;
    }
}

// ---------------- tail kernels ----------------

__global__ void k_finalmax(const float* __restrict__ pval, const int* __restrict__ pidx,
                           const float* __restrict__ svp, const int* __restrict__ gt,
                           int* __restrict__ smidx, float* __restrict__ vals, int* __restrict__ flags) {
    int j = blockIdx.x * 256 + threadIdx.x;
    if (j >= N) return;
    float bv = -2.f; int bi = 0;
    for (int c = 0; c < JC; ++c) {
        float v = pval[c * N + j];
        if (v > bv) { bv = v; bi = pidx[c * N + j]; }
    }
    smidx[j] = bi;
    float vv = svp[bi * OCH + gt[j]];
    vals[j] = vv;
    if (vv > 0.1f) atomicOr(&flags[0], 1);
}

__global__ void k_mask(const float* __restrict__ vals, const int* __restrict__ smidx,
                       const int* __restrict__ flags, int* __restrict__ winner, int* __restrict__ flags2) {
    int j = blockIdx.x * 256 + threadIdx.x;
    if (j >= N) return;
    float thr = flags[0] ? 0.1f : 0.0f;
    if (vals[j] > thr) atomicMax(&winner[smidx[j]], j);   // last-duplicate-wins (max j)
    else atomicOr(&flags2[1], 1);                          // -1 present in trust
}

__global__ void k_rowsout(const int* __restrict__ winner, const int* __restrict__ gt,
                          const float* __restrict__ svp,
                          float* __restrict__ o_svp, float* __restrict__ o_pre) {
    int i = blockIdx.x * 256 + threadIdx.x;
    if (i >= N) return;
    int w = winner[i];
    float row[OCH];
    if (w >= 0) {
        int g = gt[w];
        for (int c = 0; c < OCH; ++c) row[c] = (c == g) ? 1.f : 0.f;
    } else {
        for (int c = 0; c < OCH; ++c) row[c] = svp[i*OCH + c];
    }
    int p = 0; float m = row[0];
    for (int c = 0; c < OCH; ++c) {
        o_svp[i*OCH + c] = row[c];
        if (c > 0 && row[c] > m) { m = row[c]; p = c; }
    }
    o_pre[i] = (float)p;
}

__global__ void __launch_bounds__(1024) k_trust(const int* __restrict__ winner, const int* __restrict__ flags,
                                                float* __restrict__ out0, float* __restrict__ out5) {
    __shared__ int wsum[16];
    int tid = threadIdx.x;
    for (int p = tid; p < N; p += 1024) { out0[p] = -1.f; out5[p] = -1.f; }
    __syncthreads();
    int off = flags[1] ? 1 : 0;
    int base = 0;
    for (int round = 0; round < N; round += 1024) {
        int i = round + tid;
        int pres = (i < N && winner[i] >= 0) ? 1 : 0;
        unsigned long long mask = __ballot(pres);
        int lane = tid & 63;
        int wv = tid >> 6;
        int excl = (lane == 0) ? 0 : __popcll(mask & (~0ull >> (64 - lane)));
        if (lane == 0) wsum[wv] = __popcll(mask);
        __syncthreads();
        int wpre = 0, tot = 0;
        for (int t = 0; t < 16; ++t) { if (t < wv) wpre += wsum[t]; tot += wsum[t]; }
        int pos = base + wpre + excl + off;
        if (pres && pos < N) { out0[pos] = (float)i; out5[pos] = (float)i; }
        base += tot;
        __syncthreads();
    }
}

__global__ void k_copy(const float4* __restrict__ src, float4* __restrict__ dst, int n4) {
    int i = blockIdx.x * 256 + threadIdx.x;
    if (i < n4) dst[i] = src[i];
}

// ---------------- launch ----------------

extern "C" void kernel_launch(void* const* d_in, const int* in_sizes, int n_in,
                              void* d_out, int out_size, void* d_ws, size_t ws_size,
                              hipStream_t stream) {
    const float* sur_feat   = (const float*)d_in[0];
    const float* sur_coords = (const float*)d_in[1];
    const int*   sur_gt     = (const int*)d_in[2];
    const float* sv_prob    = (const float*)d_in[3];
    const float* mean_feat  = (const float*)d_in[4];
    const float* ori        = (const float*)d_in[5];
    const float* posses     = (const float*)d_in[6];

    float* out = (float*)d_out;
    float* o_trust  = out;
    float* o_mf     = out + 8000;
    float* o_ori    = out + 776000;
    float* o_pre    = out + 800000;
    float* o_svp    = out + 808000;
    float* o_trust2 = out + 960000;

    float* w = (float*)d_ws;
    float* diff = w;        w += 16;
    float* w1 = w;          w += NP;
    float* xn = w;          w += NP;
    float* w2 = w;          w += NP;
    float* yn = w;          w += NP;
    float* oriT = w;        w += 3*NP;
    float* alT = w;         w += 3*NP;
    float* At = w;          w += C*NP;
    float* Bt = w;          w += C*NP;
    float* svp = w;         w += N*OCH;
    float* bvec = w;        w += NP;
    float* rowpart = w;     w += JC*N;
    float* pval = w;        w += JC*N;
    int* pidx = (int*)w;    w += JC*N;
    int* smidx = (int*)w;   w += N;
    float* vals = w;        w += N;
    int* winner = (int*)w;  w += N;
    int* flags = (int*)w;   w += 8;

    dim3 b256(256);
    int g_np = (NP + 255) / 256;   // 32
    int g_n  = (N + 255) / 256;    // 32

    k_diff<<<1, 64, 0, stream>>>(posses, diff);
    k_prepA<<<g_np, b256, 0, stream>>>(mean_feat, ori, w1, xn, oriT);
    k_prepB<<<g_np, b256, 0, stream>>>(sur_feat, sur_coords, diff, w2, yn, alT);
    k_trans<<<dim3(g_np, C/4), b256, 0, stream>>>(mean_feat, At);
    k_trans<<<dim3(g_np, C/4), b256, 0, stream>>>(sur_feat, Bt);
    k_softmax<<<g_n, b256, 0, stream>>>(sv_prob, svp);
    k_init<<<g_n, b256, 0, stream>>>(winner, flags);

    k_rowsum<<<dim3(NT, JC), b256, 0, stream>>>(At, Bt, oriT, alT, w1, xn, w2, yn, rowpart);
    k_breduce<<<g_np, b256, 0, stream>>>(rowpart, bvec);
    k_argmax<<<dim3(NT, JC), b256, 0, stream>>>(At, Bt, oriT, alT, w1, xn, w2, yn, bvec, pval, pidx);

    k_finalmax<<<g_n, b256, 0, stream>>>(pval, pidx, svp, sur_gt, smidx, vals, flags);
    k_mask<<<g_n, b256, 0, stream>>>(vals, smidx, flags, winner, flags);
    k_rowsout<<<g_n, b256, 0, stream>>>(winner, sur_gt, svp, o_svp, o_pre);
    k_trust<<<1, 1024, 0, stream>>>(winner, flags, o_trust, o_trust2);

    k_copy<<<(768000/4 + 255)/256, b256, 0, stream>>>((const float4*)mean_feat, (float4*)o_mf, 768000/4);
    k_copy<<<(24000/4 + 255)/256, b256, 0, stream>>>((const float4*)ori, (float4*)o_ori, 24000/4);
}

// Round 2
// 214.343 us; speedup vs baseline: 3.6943x; 3.6943x over previous
//
#include <hip/hip_runtime.h>

#define N 8000
#define C 96
#define C4 24
#define OCH 19
#define NCELL 1000
#define NCH 32
#define HSZ (NCELL*NCH)
#define U1 (1.0f/8000.0f)

// ---------------- small setup kernels ----------------

__global__ void k_diff(const float* __restrict__ posses, float* __restrict__ diff) {
    if (threadIdx.x != 0 || blockIdx.x != 0) return;
    double M[4][8];
    for (int r = 0; r < 4; ++r)
        for (int c = 0; c < 4; ++c) {
            M[r][c] = (double)posses[16 + r*4 + c];
            M[r][4+c] = (r == c) ? 1.0 : 0.0;
        }
    for (int col = 0; col < 4; ++col) {
        int piv = col; double best = fabs(M[col][col]);
        for (int r = col+1; r < 4; ++r) { double v = fabs(M[r][col]); if (v > best) { best = v; piv = r; } }
        if (piv != col) for (int c = 0; c < 8; ++c) { double t = M[col][c]; M[col][c] = M[piv][c]; M[piv][c] = t; }
        double inv = 1.0 / M[col][col];
        for (int c = 0; c < 8; ++c) M[col][c] *= inv;
        for (int r = 0; r < 4; ++r) if (r != col) {
            double f = M[r][col];
            for (int c = 0; c < 8; ++c) M[r][c] -= f * M[col][c];
        }
    }
    for (int r = 0; r < 4; ++r)
        for (int c = 0; c < 4; ++c) {
            double s = 0.0;
            for (int k = 0; k < 4; ++k) s += M[r][4+k] * (double)posses[k*4 + c];
            diff[r*4 + c] = (float)s;
        }
}

__device__ __forceinline__ int clamp10(int v) { return min(max(v, 0), 9); }

__global__ void k_zero(int* __restrict__ histA, int* __restrict__ histB) {
    int i = blockIdx.x * 256 + threadIdx.x;
    if (i < HSZ) { histA[i] = 0; histB[i] = 0; }
}

// i-side: w1 = ||mean_features||, cell of ori coords, histogram
__global__ void k_prepA(const float* __restrict__ mf, const float* __restrict__ ori,
                        float* __restrict__ w1, int* __restrict__ cellA, int* __restrict__ histA) {
    int i = blockIdx.x * 256 + threadIdx.x;
    if (i >= N) return;
    const float4* m4 = (const float4*)mf + i*C4;
    float s = 0.f;
    for (int kk = 0; kk < C4; ++kk) {
        float4 v = m4[kk];
        s += v.x*v.x; s += v.y*v.y; s += v.z*v.z; s += v.w*v.w;
    }
    w1[i] = sqrtf(s);
    float ox = ori[i*3], oy = ori[i*3+1], oz = ori[i*3+2];
    int cx = clamp10((int)floorf((ox + 25.f) * 0.2f));
    int cy = clamp10((int)floorf((oy + 25.f) * 0.2f));
    int cz = clamp10((int)floorf((oz + 25.f) * 0.2f));
    int c = (cz*10 + cy)*10 + cx;
    cellA[i] = c;
    atomicAdd(&histA[c*NCH + (i >> 8)], 1);
}

// j-side: al transform, yn, w2, cell, histogram
__global__ void k_prepB(const float* __restrict__ sf, const float* __restrict__ coords,
                        const float* __restrict__ diff,
                        float* __restrict__ w2, float4* __restrict__ alN,
                        int* __restrict__ cellB, int* __restrict__ histB) {
    int j = blockIdx.x * 256 + threadIdx.x;
    if (j >= N) return;
    const float4* s4 = (const float4*)sf + j*C4;
    float s = 0.f;
    for (int kk = 0; kk < C4; ++kk) {
        float4 v = s4[kk];
        s += v.x*v.x; s += v.y*v.y; s += v.z*v.z; s += v.w*v.w;
    }
    w2[j] = sqrtf(s);
    float c0 = coords[j*3], c1 = coords[j*3+1], c2 = coords[j*3+2];
    float a0 = (diff[0]*c0 + diff[1]*c1) + (diff[2]*c2 + diff[3]);
    float a1 = (diff[4]*c0 + diff[5]*c1) + (diff[6]*c2 + diff[7]);
    float a2 = (diff[8]*c0 + diff[9]*c1) + (diff[10]*c2 + diff[11]);
    alN[j] = make_float4(a0, a1, a2, a0*a0 + a1*a1 + a2*a2);
    int cx = clamp10((int)floorf((a0 + 25.f) * 0.2f));
    int cy = clamp10((int)floorf((a1 + 25.f) * 0.2f));
    int cz = clamp10((int)floorf((a2 + 25.f) * 0.2f));
    int c = (cz*10 + cy)*10 + cx;
    cellB[j] = c;
    atomicAdd(&histB[c*NCH + (j >> 8)], 1);
}

// exclusive prefix scan over [cell][chunk] histogram (in-place), + cellStart[1001]
__global__ void __launch_bounds__(1024) k_scan(int* __restrict__ histA, int* __restrict__ histB,
                                               int* __restrict__ csA, int* __restrict__ csB) {
    int* h  = blockIdx.x ? histB : histA;
    int* cs = blockIdx.x ? csB : csA;
    int tid = threadIdx.x;
    int base = tid * 32;
    int v[32]; int s = 0;
    #pragma unroll
    for (int t = 0; t < 32; ++t) { int idx = base + t; int x = (idx < HSZ) ? h[idx] : 0; v[t] = x; s += x; }
    int lane = tid & 63, wv = tid >> 6;
    int x = s;
    for (int off = 1; off < 64; off <<= 1) { int y = __shfl_up(x, off); if (lane >= off) x += y; }
    __shared__ int wtot[16];
    if (lane == 63) wtot[wv] = x;
    __syncthreads();
    int wpre = 0;
    for (int t = 0; t < 16; ++t) if (t < wv) wpre += wtot[t];
    int run = wpre + x - s;   // exclusive prefix of this thread's segment
    #pragma unroll
    for (int t = 0; t < 32; ++t) { int idx = base + t; if (idx < HSZ) h[idx] = run; run += v[t]; }
    __syncthreads();
    for (int c = tid; c < NCELL; c += 1024) cs[c] = h[c*NCH];
    if (tid == 0) cs[NCELL] = N;
}

// deterministic stable scatter into CSR order (ascending global index within cell)
__global__ void k_scatterA(const int* __restrict__ cellA, const int* __restrict__ startA,
                           const float* __restrict__ w1, const float* __restrict__ ori,
                           const float* __restrict__ mf,
                           int* __restrict__ idAR, float* __restrict__ w1R,
                           float4* __restrict__ oriR, float4* __restrict__ fAR) {
    __shared__ int sc[256];
    int chunk = blockIdx.x, tid = threadIdx.x;
    int gi = chunk*256 + tid;
    int cell = (gi < N) ? cellA[gi] : -1;
    sc[tid] = cell;
    __syncthreads();
    if (gi >= N) return;
    int rank = 0;
    for (int t = 0; t < tid; ++t) rank += (sc[t] == cell);
    int pos = startA[cell*NCH + chunk] + rank;
    idAR[pos] = gi;
    w1R[pos] = w1[gi];
    float ox = ori[gi*3], oy = ori[gi*3+1], oz = ori[gi*3+2];
    oriR[pos] = make_float4(ox, oy, oz, ox*ox + oy*oy + oz*oz);
    const float4* src = (const float4*)mf + gi*C4;
    for (int kk = 0; kk < C4; ++kk) fAR[kk*N + pos] = src[kk];
}

__global__ void k_scatterB(const int* __restrict__ cellB, const int* __restrict__ startB,
                           const float* __restrict__ w2, const float4* __restrict__ alN,
                           const float* __restrict__ sf,
                           float* __restrict__ w2R, float4* __restrict__ alR, float4* __restrict__ fBR) {
    __shared__ int sc[256];
    int chunk = blockIdx.x, tid = threadIdx.x;
    int gi = chunk*256 + tid;
    int cell = (gi < N) ? cellB[gi] : -1;
    sc[tid] = cell;
    __syncthreads();
    if (gi >= N) return;
    int rank = 0;
    for (int t = 0; t < tid; ++t) rank += (sc[t] == cell);
    int pos = startB[cell*NCH + chunk] + rank;
    w2R[pos] = w2[gi];
    alR[pos] = alN[gi];
    const float4* src = (const float4*)sf + gi*C4;
    for (int kk = 0; kk < C4; ++kk) fBR[kk*N + pos] = src[kk];
}

__global__ void k_softmax(const float* __restrict__ p, float* __restrict__ svp) {
    int i = blockIdx.x * 256 + threadIdx.x;
    if (i >= N) return;
    float m = -1e30f;
    for (int c = 0; c < OCH; ++c) m = fmaxf(m, p[i*OCH + c]);
    float e[OCH]; float s = 0.f;
    for (int c = 0; c < OCH; ++c) { e[c] = expf(p[i*OCH + c] - m); s += e[c]; }
    for (int c = 0; c < OCH; ++c) svp[i*OCH + c] = e[c] / s;
}

__global__ void k_init(int* __restrict__ winner, int* __restrict__ flags) {
    int i = blockIdx.x * 256 + threadIdx.x;
    if (i < N) winner[i] = -1;
    if (i == 0) { flags[0] = 0; flags[1] = 0; }
}

// ---------------- sparse passes ----------------
// K(i,j) = exp(-((1 + (1 - dot/max(w1*w2,1e-8))) - exp(-0.5*cd)) / 0.03), cd = max(xn+yn-2<ori,al>,0)*4, iff cd<100

// pass1: per i (CSR-A order), rowsum over supported j -> bR[p] = U1/(sum+1e-16)
__global__ void __launch_bounds__(256) k_pass1(
    const float4* __restrict__ mf4, const int* __restrict__ idAR,
    const float4* __restrict__ oriR, const float* __restrict__ w1R,
    const float4* __restrict__ alR, const float* __restrict__ w2R,
    const float4* __restrict__ fBR, const int* __restrict__ csB,
    float* __restrict__ bR) {
    __shared__ float4 sRow[4][C4];
    int tid = threadIdx.x, lane = tid & 63, w = tid >> 6;
    int p = blockIdx.x * 4 + w;
    int i = idAR[p];
    if (lane < C4) sRow[w][lane] = mf4[i*C4 + lane];
    __syncthreads();
    float4 oi = oriR[p];
    float w1v = w1R[p];
    int cx = clamp10((int)floorf((oi.x + 25.f) * 0.2f));
    int cy = clamp10((int)floorf((oi.y + 25.f) * 0.2f));
    int cz = clamp10((int)floorf((oi.z + 25.f) * 0.2f));
    int xlo = max(cx-1, 0), xhi = min(cx+1, 9);
    float racc = 0.f;
    for (int dz = -1; dz <= 1; ++dz) {
        int z = cz + dz; if ((unsigned)z > 9u) continue;
        for (int dy = -1; dy <= 1; ++dy) {
            int y = cy + dy; if ((unsigned)y > 9u) continue;
            int cbase = (z*10 + y)*10;
            int s = csB[cbase + xlo], e = csB[cbase + xhi + 1];  // 3 x-cells contiguous
            for (int q0 = s; q0 < e; q0 += 64) {
                int q = q0 + lane;
                if (q < e) {
                    float4 aj = alR[q];
                    float d = oi.w + aj.w - 2.f*(oi.x*aj.x + oi.y*aj.y + oi.z*aj.z);
                    float cd = fmaxf(d, 0.f) * 4.f;
                    if (cd < 100.f) {
                        float ax = 0.f, ay = 0.f, az = 0.f, aw = 0.f;
                        #pragma unroll 4
                        for (int kk = 0; kk < C4; ++kk) {
                            float4 a = sRow[w][kk];
                            float4 b = fBR[kk*N + q];
                            ax += a.x*b.x; ay += a.y*b.y; az += a.z*b.z; aw += a.w*b.w;
                        }
                        float dot = (ax + ay) + (az + aw);
                        float fdc = 1.f - dot / fmaxf(w1v * w2R[q], 1e-8f);
                        float dist = (1.f + fdc) - expf(-0.5f * cd);
                        racc += expf(-dist / 0.03f) * U1;
                    }
                }
            }
        }
    }
    for (int off = 32; off; off >>= 1) racc += __shfl_xor(racc, off);
    if (lane == 0) bR[p] = U1 / (racc + 1e-16f);
}

// pass2: per j (natural order), argmax_i of K(i,j)*b[i] over supported i; fused vals/flag
__global__ void __launch_bounds__(256) k_pass2(
    const float4* __restrict__ sf4, const float4* __restrict__ alN, const float* __restrict__ w2,
    const int* __restrict__ idAR, const float4* __restrict__ oriR, const float* __restrict__ w1R,
    const float* __restrict__ bR, const float4* __restrict__ fAR, const int* __restrict__ csA,
    const float* __restrict__ svp, const int* __restrict__ gt,
    int* __restrict__ smidx, float* __restrict__ vals, int* __restrict__ flags) {
    __shared__ float4 sRow[4][C4];
    int tid = threadIdx.x, lane = tid & 63, w = tid >> 6;
    int j = blockIdx.x * 4 + w;
    if (lane < C4) sRow[w][lane] = sf4[j*C4 + lane];
    __syncthreads();
    float4 aj = alN[j];
    float w2v = w2[j];
    int cx = clamp10((int)floorf((aj.x + 25.f) * 0.2f));
    int cy = clamp10((int)floorf((aj.y + 25.f) * 0.2f));
    int cz = clamp10((int)floorf((aj.z + 25.f) * 0.2f));
    int xlo = max(cx-1, 0), xhi = min(cx+1, 9);
    float best = 0.f; int bidx = 0;
    for (int dz = -1; dz <= 1; ++dz) {
        int z = cz + dz; if ((unsigned)z > 9u) continue;
        for (int dy = -1; dy <= 1; ++dy) {
            int y = cy + dy; if ((unsigned)y > 9u) continue;
            int cbase = (z*10 + y)*10;
            int s = csA[cbase + xlo], e = csA[cbase + xhi + 1];
            for (int q0 = s; q0 < e; q0 += 64) {
                int q = q0 + lane;
                if (q < e) {
                    float4 oi = oriR[q];
                    float d = oi.w + aj.w - 2.f*(oi.x*aj.x + oi.y*aj.y + oi.z*aj.z);
                    float cd = fmaxf(d, 0.f) * 4.f;
                    if (cd < 100.f) {
                        float ax = 0.f, ay = 0.f, az = 0.f, aw = 0.f;
                        #pragma unroll 4
                        for (int kk = 0; kk < C4; ++kk) {
                            float4 a = sRow[w][kk];
                            float4 b = fAR[kk*N + q];
                            ax += a.x*b.x; ay += a.y*b.y; az += a.z*b.z; aw += a.w*b.w;
                        }
                        float dot = (ax + ay) + (az + aw);
                        float fdc = 1.f - dot / fmaxf(w1R[q] * w2v, 1e-8f);
                        float dist = (1.f + fdc) - expf(-0.5f * cd);
                        float v = expf(-dist / 0.03f) * bR[q];
                        int gi = idAR[q];
                        if (v > best || (v == best && gi < bidx)) { best = v; bidx = gi; }
                    }
                }
            }
        }
    }
    for (int off = 32; off; off >>= 1) {
        float ov = __shfl_xor(best, off);
        int og = __shfl_xor(bidx, off);
        if (ov > best || (ov == best && og < bidx)) { best = ov; bidx = og; }
    }
    if (lane == 0) {
        smidx[j] = bidx;
        float vv = svp[bidx*OCH + gt[j]];
        vals[j] = vv;
        if (vv > 0.1f) atomicOr(&flags[0], 1);
    }
}

// ---------------- tail kernels ----------------

__global__ void k_mask(const float* __restrict__ vals, const int* __restrict__ smidx,
                       const int* __restrict__ flags, int* __restrict__ winner, int* __restrict__ flags2) {
    int j = blockIdx.x * 256 + threadIdx.x;
    if (j >= N) return;
    float thr = flags[0] ? 0.1f : 0.0f;
    if (vals[j] > thr) atomicMax(&winner[smidx[j]], j);   // numpy last-duplicate-wins
    else atomicOr(&flags2[1], 1);                          // -1 present in trust
}

__global__ void k_rowsout(const int* __restrict__ winner, const int* __restrict__ gt,
                          const float* __restrict__ svp,
                          float* __restrict__ o_svp, float* __restrict__ o_pre) {
    int i = blockIdx.x * 256 + threadIdx.x;
    if (i >= N) return;
    int w = winner[i];
    float row[OCH];
    if (w >= 0) {
        int g = gt[w];
        for (int c = 0; c < OCH; ++c) row[c] = (c == g) ? 1.f : 0.f;
    } else {
        for (int c = 0; c < OCH; ++c) row[c] = svp[i*OCH + c];
    }
    int p = 0; float m = row[0];
    for (int c = 0; c < OCH; ++c) {
        o_svp[i*OCH + c] = row[c];
        if (c > 0 && row[c] > m) { m = row[c]; p = c; }
    }
    o_pre[i] = (float)p;
}

__global__ void __launch_bounds__(1024) k_trust(const int* __restrict__ winner, const int* __restrict__ flags,
                                                float* __restrict__ out0, float* __restrict__ out5) {
    __shared__ int wsum[16];
    int tid = threadIdx.x;
    for (int p = tid; p < N; p += 1024) { out0[p] = -1.f; out5[p] = -1.f; }
    __syncthreads();
    int off = flags[1] ? 1 : 0;
    int base = 0;
    for (int round = 0; round < N; round += 1024) {
        int i = round + tid;
        int pres = (i < N && winner[i] >= 0) ? 1 : 0;
        unsigned long long mask = __ballot(pres);
        int lane = tid & 63;
        int wv = tid >> 6;
        int excl = (lane == 0) ? 0 : __popcll(mask & (~0ull >> (64 - lane)));
        if (lane == 0) wsum[wv] = __popcll(mask);
        __syncthreads();
        int wpre = 0, tot = 0;
        for (int t = 0; t < 16; ++t) { if (t < wv) wpre += wsum[t]; tot += wsum[t]; }
        int pos = base + wpre + excl + off;
        if (pres && pos < N) { out0[pos] = (float)i; out5[pos] = (float)i; }
        base += tot;
        __syncthreads();
    }
}

__global__ void k_copy(const float4* __restrict__ src, float4* __restrict__ dst, int n4) {
    int i = blockIdx.x * 256 + threadIdx.x;
    if (i < n4) dst[i] = src[i];
}

// ---------------- launch ----------------

extern "C" void kernel_launch(void* const* d_in, const int* in_sizes, int n_in,
                              void* d_out, int out_size, void* d_ws, size_t ws_size,
                              hipStream_t stream) {
    const float* sur_feat   = (const float*)d_in[0];
    const float* sur_coords = (const float*)d_in[1];
    const int*   sur_gt     = (const int*)d_in[2];
    const float* sv_prob    = (const float*)d_in[3];
    const float* mean_feat  = (const float*)d_in[4];
    const float* ori        = (const float*)d_in[5];
    const float* posses     = (const float*)d_in[6];

    float* out = (float*)d_out;
    float* o_trust  = out;
    float* o_mf     = out + 8000;
    float* o_ori    = out + 776000;
    float* o_pre    = out + 800000;
    float* o_svp    = out + 808000;
    float* o_trust2 = out + 960000;

    float* w = (float*)d_ws;
    float* diff = w;        w += 16;
    float* w1 = w;          w += N;
    float* w2 = w;          w += N;
    float4* alN = (float4*)w;  w += 4*N;
    int* cellA = (int*)w;   w += N;
    int* cellB = (int*)w;   w += N;
    int* histA = (int*)w;   w += HSZ;    // scanned in-place -> startA
    int* histB = (int*)w;   w += HSZ;
    int* csA = (int*)w;     w += 1008;
    int* csB = (int*)w;     w += 1008;
    int* idAR = (int*)w;    w += N;
    float* w1R = w;         w += N;
    float* w2R = w;         w += N;
    float4* oriR = (float4*)w; w += 4*N;
    float4* alR = (float4*)w;  w += 4*N;
    float4* fAR = (float4*)w;  w += C4*4*N;
    float4* fBR = (float4*)w;  w += C4*4*N;
    float* bR = w;          w += N;
    float* svp = w;         w += N*OCH;
    int* smidx = (int*)w;   w += N;
    float* vals = w;        w += N;
    int* winner = (int*)w;  w += N;
    int* flags = (int*)w;   w += 8;

    dim3 b256(256);
    int g_n = (N + 255) / 256;   // 32

    k_zero<<<(HSZ + 255)/256, b256, 0, stream>>>(histA, histB);
    k_diff<<<1, 64, 0, stream>>>(posses, diff);
    k_prepA<<<g_n, b256, 0, stream>>>(mean_feat, ori, w1, cellA, histA);
    k_prepB<<<g_n, b256, 0, stream>>>(sur_feat, sur_coords, diff, w2, alN, cellB, histB);
    k_scan<<<2, 1024, 0, stream>>>(histA, histB, csA, csB);
    k_scatterA<<<g_n, b256, 0, stream>>>(cellA, histA, w1, ori, mean_feat, idAR, w1R, oriR, fAR);
    k_scatterB<<<g_n, b256, 0, stream>>>(cellB, histB, w2, alN, sur_feat, w2R, alR, fBR);
    k_softmax<<<g_n, b256, 0, stream>>>(sv_prob, svp);
    k_init<<<g_n, b256, 0, stream>>>(winner, flags);

    k_pass1<<<N/4, b256, 0, stream>>>((const float4*)mean_feat, idAR, oriR, w1R, alR, w2R, fBR, csB, bR);
    k_pass2<<<N/4, b256, 0, stream>>>((const float4*)sur_feat, alN, w2, idAR, oriR, w1R, bR, fAR, csA,
                                      svp, sur_gt, smidx, vals, flags);

    k_mask<<<g_n, b256, 0, stream>>>(vals, smidx, flags, winner, flags);
    k_rowsout<<<g_n, b256, 0, stream>>>(winner, sur_gt, svp, o_svp, o_pre);
    k_trust<<<1, 1024, 0, stream>>>(winner, flags, o_trust, o_trust2);

    k_copy<<<(768000/4 + 255)/256, b256, 0, stream>>>((const float4*)mean_feat, (float4*)o_mf, 768000/4);
    k_copy<<<(24000/4 + 255)/256, b256, 0, stream>>>((const float4*)ori, (float4*)o_ori, 24000/4);
}

// Round 3
// 200.641 us; speedup vs baseline: 3.9466x; 1.0683x over previous
//
#include <hip/hip_runtime.h>

#define N 8000
#define C 96
#define C4 24
#define OCH 19
#define NCELL 1000
#define NCH 32
#define HSZ (NCELL*NCH)
#define U1 (1.0f/8000.0f)
#define PAIR_CAP 256

__device__ __forceinline__ int clamp10(int v) { return min(max(v, 0), 9); }

// ---------------- fused prep: prepB (+per-block diff), softmax, output copies ----------------
__global__ void __launch_bounds__(256) k_prep(
    const float* __restrict__ sf, const float* __restrict__ coords,
    const float* __restrict__ posses, const float* __restrict__ sv_prob,
    const float* __restrict__ mf, const float* __restrict__ ori,
    float* __restrict__ w2, float4* __restrict__ alN,
    int* __restrict__ cellB, int* __restrict__ histB,
    float* __restrict__ svp,
    float* __restrict__ o_mf, float* __restrict__ o_ori) {
    int bx = blockIdx.x, tid = threadIdx.x;
    if (bx < 32) {
        __shared__ float sdiff[12];
        if (tid == 0) {
            double M[4][8];
            for (int r = 0; r < 4; ++r)
                for (int c = 0; c < 4; ++c) {
                    M[r][c] = (double)posses[16 + r*4 + c];
                    M[r][4+c] = (r == c) ? 1.0 : 0.0;
                }
            for (int col = 0; col < 4; ++col) {
                int piv = col; double best = fabs(M[col][col]);
                for (int r = col+1; r < 4; ++r) { double v = fabs(M[r][col]); if (v > best) { best = v; piv = r; } }
                if (piv != col) for (int c = 0; c < 8; ++c) { double t = M[col][c]; M[col][c] = M[piv][c]; M[piv][c] = t; }
                double inv = 1.0 / M[col][col];
                for (int c = 0; c < 8; ++c) M[col][c] *= inv;
                for (int r = 0; r < 4; ++r) if (r != col) {
                    double f = M[r][col];
                    for (int c = 0; c < 8; ++c) M[r][c] -= f * M[col][c];
                }
            }
            for (int r = 0; r < 3; ++r)
                for (int c = 0; c < 4; ++c) {
                    double s = 0.0;
                    for (int k = 0; k < 4; ++k) s += M[r][4+k] * (double)posses[k*4 + c];
                    sdiff[r*4 + c] = (float)s;
                }
        }
        __syncthreads();
        int j = bx*256 + tid;
        if (j < N) {
            const float4* s4 = (const float4*)sf + j*C4;
            float s = 0.f;
            for (int kk = 0; kk < C4; ++kk) {
                float4 v = s4[kk];
                s += v.x*v.x; s += v.y*v.y; s += v.z*v.z; s += v.w*v.w;
            }
            w2[j] = sqrtf(s);
            float c0 = coords[j*3], c1 = coords[j*3+1], c2 = coords[j*3+2];
            float a0 = (sdiff[0]*c0 + sdiff[1]*c1) + (sdiff[2]*c2 + sdiff[3]);
            float a1 = (sdiff[4]*c0 + sdiff[5]*c1) + (sdiff[6]*c2 + sdiff[7]);
            float a2 = (sdiff[8]*c0 + sdiff[9]*c1) + (sdiff[10]*c2 + sdiff[11]);
            alN[j] = make_float4(a0, a1, a2, a0*a0 + a1*a1 + a2*a2);
            int cx = clamp10((int)floorf((a0 + 25.f) * 0.2f));
            int cy = clamp10((int)floorf((a1 + 25.f) * 0.2f));
            int cz = clamp10((int)floorf((a2 + 25.f) * 0.2f));
            int cc = (cz*10 + cy)*10 + cx;
            cellB[j] = cc;
            atomicAdd(&histB[cc*NCH + bx], 1);
        }
    } else if (bx < 64) {
        int i = (bx-32)*256 + tid;
        if (i >= N) return;
        float m = -1e30f;
        for (int c = 0; c < OCH; ++c) m = fmaxf(m, sv_prob[i*OCH + c]);
        float e[OCH]; float s = 0.f;
        for (int c = 0; c < OCH; ++c) { e[c] = expf(sv_prob[i*OCH + c] - m); s += e[c]; }
        for (int c = 0; c < OCH; ++c) svp[i*OCH + c] = e[c] / s;
    } else {
        const float4* mf4 = (const float4*)mf;
        const float4* ori4 = (const float4*)ori;
        float4* omf4 = (float4*)o_mf;
        float4* oori4 = (float4*)o_ori;
        int t0 = (bx-64)*256 + tid;
        for (int t = t0; t < 198000; t += 192*256) {
            if (t < 192000) omf4[t] = mf4[t];
            else oori4[t-192000] = ori4[t-192000];
        }
    }
}

// ---------------- exclusive scan over [cell][chunk] histogram + cell starts ----------------
__global__ void __launch_bounds__(1024) k_scan(int* __restrict__ h, int* __restrict__ cs) {
    int tid = threadIdx.x;
    int base = tid * 32;
    int v[32]; int s = 0;
    #pragma unroll
    for (int t = 0; t < 32; ++t) { int idx = base + t; int x = (idx < HSZ) ? h[idx] : 0; v[t] = x; s += x; }
    int lane = tid & 63, wv = tid >> 6;
    int x = s;
    for (int off = 1; off < 64; off <<= 1) { int y = __shfl_up(x, off); if (lane >= off) x += y; }
    __shared__ int wtot[16];
    if (lane == 63) wtot[wv] = x;
    __syncthreads();
    int wpre = 0;
    for (int t = 0; t < 16; ++t) if (t < wv) wpre += wtot[t];
    int run = wpre + x - s;
    #pragma unroll
    for (int t = 0; t < 32; ++t) { int idx = base + t; if (idx < HSZ) h[idx] = run; run += v[t]; }
    __syncthreads();
    for (int c = tid; c < NCELL; c += 1024) cs[c] = h[c*NCH];
    if (tid == 0) cs[NCELL] = N;
}

// ---------------- deterministic stable scatter of j side into CSR order ----------------
__global__ void k_scatter(const int* __restrict__ cellB, const int* __restrict__ startB,
                          const float* __restrict__ w2, const float4* __restrict__ alN,
                          const float* __restrict__ sf,
                          int* __restrict__ idBR, float* __restrict__ w2R,
                          float4* __restrict__ alR, float4* __restrict__ fBR) {
    __shared__ int sc[256];
    int chunk = blockIdx.x, tid = threadIdx.x;
    int gi = chunk*256 + tid;
    int cell = (gi < N) ? cellB[gi] : -1;
    sc[tid] = cell;
    __syncthreads();
    if (gi >= N) return;
    int rank = 0;
    for (int t = 0; t < tid; ++t) rank += (sc[t] == cell);
    int pos = startB[cell*NCH + chunk] + rank;
    idBR[pos] = gi;
    w2R[pos] = w2[gi];
    alR[pos] = alN[gi];
    const float4* src = (const float4*)sf + gi*C4;
    float4* dst = fBR + pos*C4;
    for (int kk = 0; kk < C4; ++kk) dst[kk] = src[kk];
}

// ---------------- single dense pass: per row i, compact -> dot -> K -> b -> colmax ----------------
__global__ void __launch_bounds__(256) k_pairs(
    const float4* __restrict__ mf4, const float* __restrict__ ori,
    const float4* __restrict__ alR, const float* __restrict__ w2R,
    const float4* __restrict__ fBR, const int* __restrict__ idBR,
    const int* __restrict__ csB,
    unsigned long long* __restrict__ colkey) {
    __shared__ float4 sRow[4][C4];
    __shared__ int bq[4][128];
    __shared__ float bc[4][128];
    __shared__ int sJ[4][PAIR_CAP];
    __shared__ float sK[4][PAIR_CAP];

    int tid = threadIdx.x, lane = tid & 63, w = tid >> 6;
    int i = blockIdx.x * 4 + w;
    if (lane < C4) sRow[w][lane] = mf4[i*C4 + lane];
    __syncthreads();

    float ox = ori[i*3], oy = ori[i*3+1], oz = ori[i*3+2];
    float xnv = ox*ox + oy*oy + oz*oz;
    float s = 0.f;
    for (int kk = 0; kk < C4; ++kk) {
        float4 v = sRow[w][kk];
        s += v.x*v.x; s += v.y*v.y; s += v.z*v.z; s += v.w*v.w;
    }
    float w1v = sqrtf(s);

    int cx = clamp10((int)floorf((ox + 25.f) * 0.2f));
    int cy = clamp10((int)floorf((oy + 25.f) * 0.2f));
    int cz = clamp10((int)floorf((oz + 25.f) * 0.2f));
    int xlo = max(cx-1, 0), xhi = min(cx+1, 9);

    int cnt = 0, done = 0, npairs = 0;
    float racc = 0.f;
    unsigned long long lmask = (lane == 0) ? 0ull : (~0ull >> (64 - lane));

    auto process = [&](int nb) {
        bool act = lane < nb;
        if (act) {
            int slot = (done + lane) & 127;
            int qq = bq[w][slot];
            float cdb = bc[w][slot];
            const float4* br = fBR + qq*C4;
            float ax = 0.f, ay = 0.f, az = 0.f, aw = 0.f;
            #pragma unroll 4
            for (int kk = 0; kk < C4; ++kk) {
                float4 a = sRow[w][kk];
                float4 b = br[kk];
                ax += a.x*b.x; ay += a.y*b.y; az += a.z*b.z; aw += a.w*b.w;
            }
            float dot = (ax + ay) + (az + aw);
            float fdc = 1.f - dot / fmaxf(w1v * w2R[qq], 1e-8f);
            float dist = (1.f + fdc) - expf(-0.5f * cdb);
            float K = expf(-dist / 0.03f);
            racc += K * U1;
            int sl = npairs + lane;
            if (sl < PAIR_CAP) { sJ[w][sl] = idBR[qq]; sK[w][sl] = K; }
        }
        npairs += nb;
        done += nb;
    };

    for (int dz = -1; dz <= 1; ++dz) {
        int z = cz + dz; if ((unsigned)z > 9u) continue;
        for (int dy = -1; dy <= 1; ++dy) {
            int y = cy + dy; if ((unsigned)y > 9u) continue;
            int cbase = (z*10 + y)*10;
            int s0 = csB[cbase + xlo], e = csB[cbase + xhi + 1];
            for (int q0 = s0; q0 < e; q0 += 64) {
                int q = q0 + lane;
                bool pass = false; float cdv = 0.f;
                if (q < e) {
                    float4 aj = alR[q];
                    float d = xnv + aj.w - 2.f*(ox*aj.x + oy*aj.y + oz*aj.z);
                    cdv = fmaxf(d, 0.f) * 4.f;
                    pass = cdv < 100.f;
                }
                unsigned long long m = __ballot(pass);
                if (pass) {
                    int slot = (cnt + __popcll(m & lmask)) & 127;
                    bq[w][slot] = q; bc[w][slot] = cdv;
                }
                cnt += __popcll(m);
                if (cnt - done >= 64) process(64);
            }
        }
    }
    if (cnt > done) process(cnt - done);

    for (int off = 32; off; off >>= 1) racc += __shfl_xor(racc, off);
    float bi = U1 / (racc + 1e-16f);

    unsigned long long ikey = (unsigned long long)(unsigned)(N - i);
    int np = min(npairs, PAIR_CAP);
    for (int t = lane; t < np; t += 64) {
        float v = sK[w][t] * bi;
        if (v > 0.f) {
            unsigned long long key = ((unsigned long long)__float_as_uint(v) << 32) | ikey;
            atomicMax(&colkey[sJ[w][t]], key);
        }
    }
}

// ---------------- decode colmax -> winner atomics under both thresholds ----------------
__global__ void k_post(const unsigned long long* __restrict__ colkey,
                       const float* __restrict__ svp, const int* __restrict__ gt,
                       int* __restrict__ winnerHi, int* __restrict__ winnerLo,
                       int* __restrict__ flags) {
    int j = blockIdx.x * 256 + threadIdx.x;
    if (j >= N) return;
    unsigned long long key = colkey[j];
    int bidx = key ? (N - (int)(key & 0xffffffffull)) : 0;
    float vv = svp[bidx*OCH + gt[j]];
    if (vv > 0.1f) { atomicMax(&winnerHi[bidx], j); atomicOr(&flags[0], 1); }
    else atomicOr(&flags[1], 1);
    if (vv > 0.0f) atomicMax(&winnerLo[bidx], j);
    else atomicOr(&flags[2], 1);
}

// ---------------- output rows ----------------
__global__ void k_rowsout(const int* __restrict__ winnerHi, const int* __restrict__ winnerLo,
                          const int* __restrict__ flags, const int* __restrict__ gt,
                          const float* __restrict__ svp,
                          float* __restrict__ o_svp, float* __restrict__ o_pre) {
    int i = blockIdx.x * 256 + threadIdx.x;
    if (i >= N) return;
    const int* winner = flags[0] ? winnerHi : winnerLo;
    int w = winner[i];
    float row[OCH];
    if (w >= 0) {
        int g = gt[w];
        for (int c = 0; c < OCH; ++c) row[c] = (c == g) ? 1.f : 0.f;
    } else {
        for (int c = 0; c < OCH; ++c) row[c] = svp[i*OCH + c];
    }
    int p = 0; float m = row[0];
    for (int c = 0; c < OCH; ++c) {
        o_svp[i*OCH + c] = row[c];
        if (c > 0 && row[c] > m) { m = row[c]; p = c; }
    }
    o_pre[i] = (float)p;
}

// ---------------- sorted-unique trust list ----------------
__global__ void __launch_bounds__(1024) k_trust(const int* __restrict__ winnerHi, const int* __restrict__ winnerLo,
                                                const int* __restrict__ flags,
                                                float* __restrict__ out0, float* __restrict__ out5) {
    __shared__ int wsum[16];
    int tid = threadIdx.x;
    const int* winner = flags[0] ? winnerHi : winnerLo;
    int off = flags[0] ? (flags[1] ? 1 : 0) : (flags[2] ? 1 : 0);
    for (int p = tid; p < N; p += 1024) { out0[p] = -1.f; out5[p] = -1.f; }
    __syncthreads();
    int base = 0;
    for (int round = 0; round < N; round += 1024) {
        int i = round + tid;
        int pres = (i < N && winner[i] >= 0) ? 1 : 0;
        unsigned long long mask = __ballot(pres);
        int lane = tid & 63;
        int wv = tid >> 6;
        int excl = (lane == 0) ? 0 : __popcll(mask & (~0ull >> (64 - lane)));
        if (lane == 0) wsum[wv] = __popcll(mask);
        __syncthreads();
        int wpre = 0, tot = 0;
        for (int t = 0; t < 16; ++t) { if (t < wv) wpre += wsum[t]; tot += wsum[t]; }
        int pos = base + wpre + excl + off;
        if (pres && pos < N) { out0[pos] = (float)i; out5[pos] = (float)i; }
        base += tot;
        __syncthreads();
    }
}

// ---------------- launch ----------------
extern "C" void kernel_launch(void* const* d_in, const int* in_sizes, int n_in,
                              void* d_out, int out_size, void* d_ws, size_t ws_size,
                              hipStream_t stream) {
    const float* sur_feat   = (const float*)d_in[0];
    const float* sur_coords = (const float*)d_in[1];
    const int*   sur_gt     = (const int*)d_in[2];
    const float* sv_prob    = (const float*)d_in[3];
    const float* mean_feat  = (const float*)d_in[4];
    const float* ori        = (const float*)d_in[5];
    const float* posses     = (const float*)d_in[6];

    float* out = (float*)d_out;
    float* o_trust  = out;
    float* o_mf     = out + 8000;
    float* o_ori    = out + 776000;
    float* o_pre    = out + 800000;
    float* o_svp    = out + 808000;
    float* o_trust2 = out + 960000;

    float* w = (float*)d_ws;
    float* w2 = w;                 w += N;
    float4* alN = (float4*)w;      w += 4*N;
    int* cellB = (int*)w;          w += N;
    // ---- contiguous zero region: histB | colkey | flags ----
    int* histB = (int*)w;          w += HSZ;
    unsigned long long* colkey = (unsigned long long*)w;  w += 4*N;   // 8000 u64 (8B aligned: offset 48000 floats)
    int* flags = (int*)w;          w += 8;
    // ---- end zero region ----
    int* csB = (int*)w;            w += 1008;
    float* svp = w;                w += N*OCH;
    int* idBR = (int*)w;           w += N;
    float* w2R = w;                w += N;
    float4* alR = (float4*)w;      w += 4*N;
    float4* fBR = (float4*)w;      w += C4*4*N;
    // ---- contiguous 0xFF region: winnerHi | winnerLo ----
    int* winnerHi = (int*)w;       w += N;
    int* winnerLo = (int*)w;       w += N;

    dim3 b256(256);

    hipMemsetAsync(histB, 0, (size_t)(HSZ + 8*N + 8) * 4, stream);
    hipMemsetAsync(winnerHi, 0xFF, (size_t)(2*N) * 4, stream);

    k_prep<<<256, b256, 0, stream>>>(sur_feat, sur_coords, posses, sv_prob, mean_feat, ori,
                                     w2, alN, cellB, histB, svp, o_mf, o_ori);
    k_scan<<<1, 1024, 0, stream>>>(histB, csB);
    k_scatter<<<32, b256, 0, stream>>>(cellB, histB, w2, alN, sur_feat, idBR, w2R, alR, fBR);
    k_pairs<<<N/4, b256, 0, stream>>>((const float4*)mean_feat, ori, alR, w2R, fBR, idBR, csB, colkey);
    k_post<<<32, b256, 0, stream>>>(colkey, svp, sur_gt, winnerHi, winnerLo, flags);
    k_rowsout<<<32, b256, 0, stream>>>(winnerHi, winnerLo, flags, sur_gt, svp, o_svp, o_pre);
    k_trust<<<1, 1024, 0, stream>>>(winnerHi, winnerLo, flags, o_trust, o_trust2);
}

// Round 4
// 123.643 us; speedup vs baseline: 6.4044x; 1.6227x over previous
//
#include <hip/hip_runtime.h>

#define N 8000
#define C 96
#define C4 24
#define OCH 19
#define NCELL 1000
#define NCH 32
#define HSZ (NCELL*NCH)
#define U1 (1.0f/8000.0f)
#define PAIR_CAP 256

__device__ __forceinline__ int clamp10(int v) { return min(max(v, 0), 9); }

// ---------------- fused prep: prepB (+per-block diff), softmax, output copies ----------------
__global__ void __launch_bounds__(256) k_prep(
    const float* __restrict__ sf, const float* __restrict__ coords,
    const float* __restrict__ posses, const float* __restrict__ sv_prob,
    const float* __restrict__ mf, const float* __restrict__ ori,
    float* __restrict__ w2, float4* __restrict__ alN,
    int* __restrict__ cellB, int* __restrict__ histB,
    float* __restrict__ svp,
    float* __restrict__ o_mf, float* __restrict__ o_ori) {
    int bx = blockIdx.x, tid = threadIdx.x;
    if (bx < 32) {
        __shared__ float sdiff[12];
        if (tid == 0) {
            double M[4][8];
            for (int r = 0; r < 4; ++r)
                for (int c = 0; c < 4; ++c) {
                    M[r][c] = (double)posses[16 + r*4 + c];
                    M[r][4+c] = (r == c) ? 1.0 : 0.0;
                }
            for (int col = 0; col < 4; ++col) {
                int piv = col; double best = fabs(M[col][col]);
                for (int r = col+1; r < 4; ++r) { double v = fabs(M[r][col]); if (v > best) { best = v; piv = r; } }
                if (piv != col) for (int c = 0; c < 8; ++c) { double t = M[col][c]; M[col][c] = M[piv][c]; M[piv][c] = t; }
                double inv = 1.0 / M[col][col];
                for (int c = 0; c < 8; ++c) M[col][c] *= inv;
                for (int r = 0; r < 4; ++r) if (r != col) {
                    double f = M[r][col];
                    for (int c = 0; c < 8; ++c) M[r][c] -= f * M[col][c];
                }
            }
            for (int r = 0; r < 3; ++r)
                for (int c = 0; c < 4; ++c) {
                    double s = 0.0;
                    for (int k = 0; k < 4; ++k) s += M[r][4+k] * (double)posses[k*4 + c];
                    sdiff[r*4 + c] = (float)s;
                }
        }
        __syncthreads();
        int j = bx*256 + tid;
        if (j < N) {
            const float4* s4 = (const float4*)sf + j*C4;
            float s = 0.f;
            for (int kk = 0; kk < C4; ++kk) {
                float4 v = s4[kk];
                s += v.x*v.x; s += v.y*v.y; s += v.z*v.z; s += v.w*v.w;
            }
            w2[j] = sqrtf(s);
            float c0 = coords[j*3], c1 = coords[j*3+1], c2 = coords[j*3+2];
            float a0 = (sdiff[0]*c0 + sdiff[1]*c1) + (sdiff[2]*c2 + sdiff[3]);
            float a1 = (sdiff[4]*c0 + sdiff[5]*c1) + (sdiff[6]*c2 + sdiff[7]);
            float a2 = (sdiff[8]*c0 + sdiff[9]*c1) + (sdiff[10]*c2 + sdiff[11]);
            alN[j] = make_float4(a0, a1, a2, a0*a0 + a1*a1 + a2*a2);
            int cx = clamp10((int)floorf((a0 + 25.f) * 0.2f));
            int cy = clamp10((int)floorf((a1 + 25.f) * 0.2f));
            int cz = clamp10((int)floorf((a2 + 25.f) * 0.2f));
            int cc = (cz*10 + cy)*10 + cx;
            cellB[j] = cc;
            atomicAdd(&histB[cc*NCH + bx], 1);
        }
    } else if (bx < 64) {
        int i = (bx-32)*256 + tid;
        if (i >= N) return;
        float m = -1e30f;
        for (int c = 0; c < OCH; ++c) m = fmaxf(m, sv_prob[i*OCH + c]);
        float e[OCH]; float s = 0.f;
        for (int c = 0; c < OCH; ++c) { e[c] = expf(sv_prob[i*OCH + c] - m); s += e[c]; }
        for (int c = 0; c < OCH; ++c) svp[i*OCH + c] = e[c] / s;
    } else {
        const float4* mf4 = (const float4*)mf;
        const float4* ori4 = (const float4*)ori;
        float4* omf4 = (float4*)o_mf;
        float4* oori4 = (float4*)o_ori;
        int t0 = (bx-64)*256 + tid;
        for (int t = t0; t < 198000; t += 192*256) {
            if (t < 192000) omf4[t] = mf4[t];
            else oori4[t-192000] = ori4[t-192000];
        }
    }
}

// ---------------- exclusive scan over [cell][chunk] histogram + cell starts ----------------
__global__ void __launch_bounds__(1024) k_scan(int* __restrict__ h, int* __restrict__ cs) {
    int tid = threadIdx.x;
    int base = tid * 32;
    int v[32]; int s = 0;
    #pragma unroll
    for (int t = 0; t < 32; ++t) { int idx = base + t; int x = (idx < HSZ) ? h[idx] : 0; v[t] = x; s += x; }
    int lane = tid & 63, wv = tid >> 6;
    int x = s;
    for (int off = 1; off < 64; off <<= 1) { int y = __shfl_up(x, off); if (lane >= off) x += y; }
    __shared__ int wtot[16];
    if (lane == 63) wtot[wv] = x;
    __syncthreads();
    int wpre = 0;
    for (int t = 0; t < 16; ++t) if (t < wv) wpre += wtot[t];
    int run = wpre + x - s;
    #pragma unroll
    for (int t = 0; t < 32; ++t) { int idx = base + t; if (idx < HSZ) h[idx] = run; run += v[t]; }
    __syncthreads();
    for (int c = tid; c < NCELL; c += 1024) cs[c] = h[c*NCH];
    if (tid == 0) cs[NCELL] = N;
}

// ---------------- deterministic stable scatter of j side into CSR order ----------------
__global__ void k_scatter(const int* __restrict__ cellB, const int* __restrict__ startB,
                          const float* __restrict__ w2, const float4* __restrict__ alN,
                          const float* __restrict__ sf,
                          int* __restrict__ idBR, float* __restrict__ w2R,
                          float4* __restrict__ alR, float4* __restrict__ fBR) {
    __shared__ int sc[256];
    int chunk = blockIdx.x, tid = threadIdx.x;
    int gi = chunk*256 + tid;
    int cell = (gi < N) ? cellB[gi] : -1;
    sc[tid] = cell;
    __syncthreads();
    if (gi >= N) return;
    int rank = 0;
    for (int t = 0; t < tid; ++t) rank += (sc[t] == cell);
    int pos = startB[cell*NCH + chunk] + rank;
    idBR[pos] = gi;
    w2R[pos] = w2[gi];
    alR[pos] = alN[gi];
    const float4* src = (const float4*)sf + gi*C4;
    float4* dst = fBR + pos*C4;
    for (int kk = 0; kk < C4; ++kk) dst[kk] = src[kk];
}

// ---------------- single dense pass: per row i, compact -> dot -> K -> b -> colmax ----------------
__global__ void __launch_bounds__(256) k_pairs(
    const float4* __restrict__ mf4, const float* __restrict__ ori,
    const float4* __restrict__ alR, const float* __restrict__ w2R,
    const float4* __restrict__ fBR, const int* __restrict__ idBR,
    const int* __restrict__ csB,
    unsigned long long* __restrict__ colkey) {
    __shared__ float4 sRow[4][C4];
    __shared__ int bq[4][128];
    __shared__ float bc[4][128];
    __shared__ int sJ[4][PAIR_CAP];
    __shared__ float sK[4][PAIR_CAP];

    int tid = threadIdx.x, lane = tid & 63, w = tid >> 6;
    int i = blockIdx.x * 4 + w;
    if (lane < C4) sRow[w][lane] = mf4[i*C4 + lane];
    __syncthreads();

    float ox = ori[i*3], oy = ori[i*3+1], oz = ori[i*3+2];
    float xnv = ox*ox + oy*oy + oz*oz;
    float s = 0.f;
    for (int kk = 0; kk < C4; ++kk) {
        float4 v = sRow[w][kk];
        s += v.x*v.x; s += v.y*v.y; s += v.z*v.z; s += v.w*v.w;
    }
    float w1v = sqrtf(s);

    int cx = clamp10((int)floorf((ox + 25.f) * 0.2f));
    int cy = clamp10((int)floorf((oy + 25.f) * 0.2f));
    int cz = clamp10((int)floorf((oz + 25.f) * 0.2f));
    int xlo = max(cx-1, 0), xhi = min(cx+1, 9);

    int cnt = 0, done = 0, npairs = 0;
    float racc = 0.f;
    unsigned long long lmask = (lane == 0) ? 0ull : (~0ull >> (64 - lane));

    auto process = [&](int nb) {
        bool act = lane < nb;
        if (act) {
            int slot = (done + lane) & 127;
            int qq = bq[w][slot];
            float cdb = bc[w][slot];
            const float4* br = fBR + qq*C4;
            float ax = 0.f, ay = 0.f, az = 0.f, aw = 0.f;
            #pragma unroll 4
            for (int kk = 0; kk < C4; ++kk) {
                float4 a = sRow[w][kk];
                float4 b = br[kk];
                ax += a.x*b.x; ay += a.y*b.y; az += a.z*b.z; aw += a.w*b.w;
            }
            float dot = (ax + ay) + (az + aw);
            float fdc = 1.f - dot / fmaxf(w1v * w2R[qq], 1e-8f);
            float dist = (1.f + fdc) - expf(-0.5f * cdb);
            float K = expf(-dist / 0.03f);
            racc += K * U1;
            int sl = npairs + lane;
            if (sl < PAIR_CAP) { sJ[w][sl] = idBR[qq]; sK[w][sl] = K; }
        }
        npairs += nb;
        done += nb;
    };

    for (int dz = -1; dz <= 1; ++dz) {
        int z = cz + dz; if ((unsigned)z > 9u) continue;
        for (int dy = -1; dy <= 1; ++dy) {
            int y = cy + dy; if ((unsigned)y > 9u) continue;
            int cbase = (z*10 + y)*10;
            int s0 = csB[cbase + xlo], e = csB[cbase + xhi + 1];
            for (int q0 = s0; q0 < e; q0 += 64) {
                int q = q0 + lane;
                bool pass = false; float cdv = 0.f;
                if (q < e) {
                    float4 aj = alR[q];
                    float d = xnv + aj.w - 2.f*(ox*aj.x + oy*aj.y + oz*aj.z);
                    cdv = fmaxf(d, 0.f) * 4.f;
                    pass = cdv < 100.f;
                }
                unsigned long long m = __ballot(pass);
                if (pass) {
                    int slot = (cnt + __popcll(m & lmask)) & 127;
                    bq[w][slot] = q; bc[w][slot] = cdv;
                }
                cnt += __popcll(m);
                if (cnt - done >= 64) process(64);
            }
        }
    }
    if (cnt > done) process(cnt - done);

    for (int off = 32; off; off >>= 1) racc += __shfl_xor(racc, off);
    float bi = U1 / (racc + 1e-16f);

    unsigned long long ikey = (unsigned long long)(unsigned)(N - i);
    int np = min(npairs, PAIR_CAP);
    for (int t = lane; t < np; t += 64) {
        float v = sK[w][t] * bi;
        if (v > 0.f) {
            unsigned long long key = ((unsigned long long)__float_as_uint(v) << 32) | ikey;
            atomicMax(&colkey[sJ[w][t]], key);
        }
    }
}

// ---------------- decode colmax -> winner atomics; wave-aggregated flag atomics ----------------
__global__ void k_post(const unsigned long long* __restrict__ colkey,
                       const float* __restrict__ svp, const int* __restrict__ gt,
                       int* __restrict__ winnerHi, int* __restrict__ winnerLo,
                       int* __restrict__ flags) {
    int j = blockIdx.x * 256 + threadIdx.x;
    int lane = threadIdx.x & 63;
    bool valid = j < N;
    float vv = 0.f; int bidx = 0;
    if (valid) {
        unsigned long long key = colkey[j];
        bidx = key ? (N - (int)(key & 0xffffffffull)) : 0;
        vv = svp[bidx*OCH + gt[j]];
    }
    bool hi = valid && (vv > 0.1f);
    bool nothi = valid && !(vv > 0.1f);
    bool lo = valid && (vv > 0.0f);
    bool notlo = valid && !(vv > 0.0f);
    if (hi) atomicMax(&winnerHi[bidx], j);
    if (lo) atomicMax(&winnerLo[bidx], j);
    // wave-level aggregation: one flag atomic per wave per condition (Guideline 12)
    unsigned long long m0 = __ballot(hi);
    unsigned long long m1 = __ballot(nothi);
    unsigned long long m2 = __ballot(notlo);
    if (lane == 0) {
        if (m0) atomicOr(&flags[0], 1);
        if (m1) atomicOr(&flags[1], 1);
        if (m2) atomicOr(&flags[2], 1);
    }
}

// ---------------- output rows ----------------
__global__ void k_rowsout(const int* __restrict__ winnerHi, const int* __restrict__ winnerLo,
                          const int* __restrict__ flags, const int* __restrict__ gt,
                          const float* __restrict__ svp,
                          float* __restrict__ o_svp, float* __restrict__ o_pre) {
    int i = blockIdx.x * 256 + threadIdx.x;
    if (i >= N) return;
    const int* winner = flags[0] ? winnerHi : winnerLo;
    int w = winner[i];
    float row[OCH];
    if (w >= 0) {
        int g = gt[w];
        for (int c = 0; c < OCH; ++c) row[c] = (c == g) ? 1.f : 0.f;
    } else {
        for (int c = 0; c < OCH; ++c) row[c] = svp[i*OCH + c];
    }
    int p = 0; float m = row[0];
    for (int c = 0; c < OCH; ++c) {
        o_svp[i*OCH + c] = row[c];
        if (c > 0 && row[c] > m) { m = row[c]; p = c; }
    }
    o_pre[i] = (float)p;
}

// ---------------- sorted-unique trust list ----------------
__global__ void __launch_bounds__(1024) k_trust(const int* __restrict__ winnerHi, const int* __restrict__ winnerLo,
                                                const int* __restrict__ flags,
                                                float* __restrict__ out0, float* __restrict__ out5) {
    __shared__ int wsum[16];
    int tid = threadIdx.x;
    const int* winner = flags[0] ? winnerHi : winnerLo;
    int off = flags[0] ? (flags[1] ? 1 : 0) : (flags[2] ? 1 : 0);
    for (int p = tid; p < N; p += 1024) { out0[p] = -1.f; out5[p] = -1.f; }
    __syncthreads();
    int base = 0;
    for (int round = 0; round < N; round += 1024) {
        int i = round + tid;
        int pres = (i < N && winner[i] >= 0) ? 1 : 0;
        unsigned long long mask = __ballot(pres);
        int lane = tid & 63;
        int wv = tid >> 6;
        int excl = (lane == 0) ? 0 : __popcll(mask & (~0ull >> (64 - lane)));
        if (lane == 0) wsum[wv] = __popcll(mask);
        __syncthreads();
        int wpre = 0, tot = 0;
        for (int t = 0; t < 16; ++t) { if (t < wv) wpre += wsum[t]; tot += wsum[t]; }
        int pos = base + wpre + excl + off;
        if (pres && pos < N) { out0[pos] = (float)i; out5[pos] = (float)i; }
        base += tot;
        __syncthreads();
    }
}

// ---------------- launch ----------------
extern "C" void kernel_launch(void* const* d_in, const int* in_sizes, int n_in,
                              void* d_out, int out_size, void* d_ws, size_t ws_size,
                              hipStream_t stream) {
    const float* sur_feat   = (const float*)d_in[0];
    const float* sur_coords = (const float*)d_in[1];
    const int*   sur_gt     = (const int*)d_in[2];
    const float* sv_prob    = (const float*)d_in[3];
    const float* mean_feat  = (const float*)d_in[4];
    const float* ori        = (const float*)d_in[5];
    const float* posses     = (const float*)d_in[6];

    float* out = (float*)d_out;
    float* o_trust  = out;
    float* o_mf     = out + 8000;
    float* o_ori    = out + 776000;
    float* o_pre    = out + 800000;
    float* o_svp    = out + 808000;
    float* o_trust2 = out + 960000;

    float* w = (float*)d_ws;
    float* w2 = w;                 w += N;
    float4* alN = (float4*)w;      w += 4*N;
    int* cellB = (int*)w;          w += N;
    // ---- contiguous zero region: histB | colkey | flags ----
    int* histB = (int*)w;          w += HSZ;
    unsigned long long* colkey = (unsigned long long*)w;  w += 4*N;   // 8000 u64 (8B aligned)
    int* flags = (int*)w;          w += 8;
    // ---- end zero region ----
    int* csB = (int*)w;            w += 1008;
    float* svp = w;                w += N*OCH;
    int* idBR = (int*)w;           w += N;
    float* w2R = w;                w += N;
    float4* alR = (float4*)w;      w += 4*N;
    float4* fBR = (float4*)w;      w += C4*4*N;
    // ---- contiguous 0xFF region: winnerHi | winnerLo ----
    int* winnerHi = (int*)w;       w += N;
    int* winnerLo = (int*)w;       w += N;

    dim3 b256(256);

    hipMemsetAsync(histB, 0, (size_t)(HSZ + 8*N + 8) * 4, stream);
    hipMemsetAsync(winnerHi, 0xFF, (size_t)(2*N) * 4, stream);

    k_prep<<<256, b256, 0, stream>>>(sur_feat, sur_coords, posses, sv_prob, mean_feat, ori,
                                     w2, alN, cellB, histB, svp, o_mf, o_ori);
    k_scan<<<1, 1024, 0, stream>>>(histB, csB);
    k_scatter<<<32, b256, 0, stream>>>(cellB, histB, w2, alN, sur_feat, idBR, w2R, alR, fBR);
    k_pairs<<<N/4, b256, 0, stream>>>((const float4*)mean_feat, ori, alR, w2R, fBR, idBR, csB, colkey);
    k_post<<<32, b256, 0, stream>>>(colkey, svp, sur_gt, winnerHi, winnerLo, flags);
    k_rowsout<<<32, b256, 0, stream>>>(winnerHi, winnerLo, flags, sur_gt, svp, o_svp, o_pre);
    k_trust<<<1, 1024, 0, stream>>>(winnerHi, winnerLo, flags, o_trust, o_trust2);
}

// Round 5
// 110.880 us; speedup vs baseline: 7.1416x; 1.1151x over previous
//
#include <hip/hip_runtime.h>

#define N 8000
#define C 96
#define C4 24
#define OCH 19
#define NCELL 1000
#define NCH 32
#define HSZ (NCELL*NCH)
#define U1 (1.0f/8000.0f)
#define PAIR_CAP 256

__device__ __forceinline__ int clamp10(int v) { return min(max(v, 0), 9); }

// ---------------- fused prep: prepB (+per-block diff), softmax, copies + ws init ----------------
__global__ void __launch_bounds__(256) k_prep(
    const float* __restrict__ sf, const float* __restrict__ coords,
    const float* __restrict__ posses, const float* __restrict__ sv_prob,
    const float* __restrict__ mf, const float* __restrict__ ori,
    float* __restrict__ w2, float4* __restrict__ alN,
    int* __restrict__ cellB, int* __restrict__ histB,
    float* __restrict__ svp,
    float* __restrict__ o_mf, float* __restrict__ o_ori,
    float4* __restrict__ ck4, int4* __restrict__ wn4, int* __restrict__ flags) {
    int bx = blockIdx.x, tid = threadIdx.x;
    if (bx < 32) {
        __shared__ float sdiff[12];
        if (tid == 0) {
            double M[4][8];
            for (int r = 0; r < 4; ++r)
                for (int c = 0; c < 4; ++c) {
                    M[r][c] = (double)posses[16 + r*4 + c];
                    M[r][4+c] = (r == c) ? 1.0 : 0.0;
                }
            for (int col = 0; col < 4; ++col) {
                int piv = col; double best = fabs(M[col][col]);
                for (int r = col+1; r < 4; ++r) { double v = fabs(M[r][col]); if (v > best) { best = v; piv = r; } }
                if (piv != col) for (int c = 0; c < 8; ++c) { double t = M[col][c]; M[col][c] = M[piv][c]; M[piv][c] = t; }
                double inv = 1.0 / M[col][col];
                for (int c = 0; c < 8; ++c) M[col][c] *= inv;
                for (int r = 0; r < 4; ++r) if (r != col) {
                    double f = M[r][col];
                    for (int c = 0; c < 8; ++c) M[r][c] -= f * M[col][c];
                }
            }
            for (int r = 0; r < 3; ++r)
                for (int c = 0; c < 4; ++c) {
                    double s = 0.0;
                    for (int k = 0; k < 4; ++k) s += M[r][4+k] * (double)posses[k*4 + c];
                    sdiff[r*4 + c] = (float)s;
                }
        }
        __syncthreads();
        int j = bx*256 + tid;
        if (j < N) {
            const float4* s4 = (const float4*)sf + j*C4;
            float s = 0.f;
            for (int kk = 0; kk < C4; ++kk) {
                float4 v = s4[kk];
                s += v.x*v.x; s += v.y*v.y; s += v.z*v.z; s += v.w*v.w;
            }
            w2[j] = sqrtf(s);
            float c0 = coords[j*3], c1 = coords[j*3+1], c2 = coords[j*3+2];
            float a0 = (sdiff[0]*c0 + sdiff[1]*c1) + (sdiff[2]*c2 + sdiff[3]);
            float a1 = (sdiff[4]*c0 + sdiff[5]*c1) + (sdiff[6]*c2 + sdiff[7]);
            float a2 = (sdiff[8]*c0 + sdiff[9]*c1) + (sdiff[10]*c2 + sdiff[11]);
            alN[j] = make_float4(a0, a1, a2, a0*a0 + a1*a1 + a2*a2);
            int cx = clamp10((int)floorf((a0 + 25.f) * 0.2f));
            int cy = clamp10((int)floorf((a1 + 25.f) * 0.2f));
            int cz = clamp10((int)floorf((a2 + 25.f) * 0.2f));
            int cc = (cz*10 + cy)*10 + cx;
            cellB[j] = cc;
            atomicAdd(&histB[cc*NCH + bx], 1);
        }
    } else if (bx < 64) {
        int i = (bx-32)*256 + tid;
        if (i >= N) return;
        float m = -1e30f;
        for (int c = 0; c < OCH; ++c) m = fmaxf(m, sv_prob[i*OCH + c]);
        float e[OCH]; float s = 0.f;
        for (int c = 0; c < OCH; ++c) { e[c] = expf(sv_prob[i*OCH + c] - m); s += e[c]; }
        for (int c = 0; c < OCH; ++c) svp[i*OCH + c] = e[c] / s;
    } else {
        // copies + workspace init (colkey zero, winnerHi|winnerLo 0xFF, flags zero)
        const float4* mf4 = (const float4*)mf;
        const float4* ori4 = (const float4*)ori;
        float4* omf4 = (float4*)o_mf;
        float4* oori4 = (float4*)o_ori;
        float4 z4 = make_float4(0.f, 0.f, 0.f, 0.f);
        int4 f4 = make_int4(-1, -1, -1, -1);
        int t0 = (bx-64)*256 + tid;
        for (int t = t0; t < 206000; t += 192*256) {
            if (t < 192000) omf4[t] = mf4[t];
            else if (t < 198000) oori4[t-192000] = ori4[t-192000];
            else if (t < 202000) ck4[t-198000] = z4;
            else wn4[t-202000] = f4;
        }
        if (bx == 64 && tid < 8) flags[tid] = 0;
    }
}

// ---------------- exclusive scan over [cell][chunk] histogram + cell starts ----------------
__global__ void __launch_bounds__(1024) k_scan(int* __restrict__ h, int* __restrict__ cs) {
    int tid = threadIdx.x;
    int base = tid * 32;
    int v[32]; int s = 0;
    #pragma unroll
    for (int t = 0; t < 32; ++t) { int idx = base + t; int x = (idx < HSZ) ? h[idx] : 0; v[t] = x; s += x; }
    int lane = tid & 63, wv = tid >> 6;
    int x = s;
    for (int off = 1; off < 64; off <<= 1) { int y = __shfl_up(x, off); if (lane >= off) x += y; }
    __shared__ int wtot[16];
    if (lane == 63) wtot[wv] = x;
    __syncthreads();
    int wpre = 0;
    for (int t = 0; t < 16; ++t) if (t < wv) wpre += wtot[t];
    int run = wpre + x - s;
    #pragma unroll
    for (int t = 0; t < 32; ++t) { int idx = base + t; if (idx < HSZ) h[idx] = run; run += v[t]; }
    __syncthreads();
    for (int c = tid; c < NCELL; c += 1024) cs[c] = h[c*NCH];
    if (tid == 0) cs[NCELL] = N;
}

// ---------------- deterministic stable scatter (index + coords only; no feature copy) ----------------
__global__ void k_scatter(const int* __restrict__ cellB, const int* __restrict__ startB,
                          const float4* __restrict__ alN,
                          int* __restrict__ idBR, float4* __restrict__ alR) {
    __shared__ int sc[256];
    int chunk = blockIdx.x, tid = threadIdx.x;
    int gi = chunk*256 + tid;
    int cell = (gi < N) ? cellB[gi] : -1;
    sc[tid] = cell;
    __syncthreads();
    if (gi >= N) return;
    int rank = 0;
    for (int t = 0; t < tid; ++t) rank += (sc[t] == cell);
    int pos = startB[cell*NCH + chunk] + rank;
    idBR[pos] = gi;
    alR[pos] = alN[gi];
}

// ---------------- single dense pass: flattened filter -> compact -> dot -> K -> b -> colmax ----------------
__global__ void __launch_bounds__(256) k_pairs(
    const float4* __restrict__ mf4, const float* __restrict__ ori,
    const float4* __restrict__ alR, const float* __restrict__ w2,
    const float4* __restrict__ sf4, const int* __restrict__ idBR,
    const int* __restrict__ csB,
    unsigned long long* __restrict__ colkey) {
    __shared__ float4 sRow[4][C4];
    __shared__ int bq[4][128];
    __shared__ float bc[4][128];
    __shared__ int sJ[4][PAIR_CAP];
    __shared__ float sK[4][PAIR_CAP];

    int tid = threadIdx.x, lane = tid & 63, w = tid >> 6;
    int i = blockIdx.x * 4 + w;
    if (lane < C4) sRow[w][lane] = mf4[i*C4 + lane];
    __syncthreads();

    float ox = ori[i*3], oy = ori[i*3+1], oz = ori[i*3+2];
    float xnv = ox*ox + oy*oy + oz*oz;
    float s = 0.f;
    for (int kk = 0; kk < C4; ++kk) {
        float4 v = sRow[w][kk];
        s += v.x*v.x; s += v.y*v.y; s += v.z*v.z; s += v.w*v.w;
    }
    float w1v = sqrtf(s);

    int cx = clamp10((int)floorf((ox + 25.f) * 0.2f));
    int cy = clamp10((int)floorf((oy + 25.f) * 0.2f));
    int cz = clamp10((int)floorf((oz + 25.f) * 0.2f));
    int xlo = max(cx-1, 0), xhi = min(cx+1, 9);

    // flatten the 9 (dz,dy) candidate segments into one index space (static unroll, rule #20)
    int s_[9], l_[9], c_[9];
    int tot = 0;
    #pragma unroll
    for (int t = 0; t < 9; ++t) {
        int z = cz + (t/3) - 1, y = cy + (t%3) - 1;
        bool ok = ((unsigned)z <= 9u) && ((unsigned)y <= 9u);
        int ss = 0, ee = 0;
        if (ok) {
            int cbase = (z*10 + y)*10;
            ss = csB[cbase + xlo];
            ee = csB[cbase + xhi + 1];
        }
        s_[t] = ss; l_[t] = ee - ss; c_[t] = tot; tot += ee - ss;
    }

    int cnt = 0, done = 0, npairs = 0;
    float racc = 0.f;
    unsigned long long lmask = (lane == 0) ? 0ull : (~0ull >> (64 - lane));

    auto process = [&](int nb) {
        if (lane < nb) {
            int slot = (done + lane) & 127;
            int qq = bq[w][slot];
            float cdb = bc[w][slot];
            int gi = idBR[qq];
            const float4* br = sf4 + gi*C4;
            float ax = 0.f, ay = 0.f, az = 0.f, aw = 0.f;
            #pragma unroll 4
            for (int kk = 0; kk < C4; ++kk) {
                float4 a = sRow[w][kk];
                float4 b = br[kk];
                ax += a.x*b.x; ay += a.y*b.y; az += a.z*b.z; aw += a.w*b.w;
            }
            float dot = (ax + ay) + (az + aw);
            float fdc = 1.f - dot / fmaxf(w1v * w2[gi], 1e-8f);
            float dist = (1.f + fdc) - expf(-0.5f * cdb);
            float K = expf(-dist / 0.03f);
            racc += K * U1;
            int sl = npairs + lane;
            if (sl < PAIR_CAP) { sJ[w][sl] = gi; sK[w][sl] = K; }
        }
        npairs += nb;
        done += nb;
    };

    for (int f0 = 0; f0 < tot; f0 += 64) {
        int f = f0 + lane;
        bool act = f < tot;
        int q = 0;
        #pragma unroll
        for (int t = 0; t < 9; ++t) {
            bool in = (f >= c_[t]) && (f - c_[t] < l_[t]);
            if (in) q = s_[t] + (f - c_[t]);
        }
        bool pass = false; float cdv = 0.f;
        if (act) {
            float4 aj = alR[q];
            float d = xnv + aj.w - 2.f*(ox*aj.x + oy*aj.y + oz*aj.z);
            cdv = fmaxf(d, 0.f) * 4.f;
            pass = cdv < 100.f;
        }
        unsigned long long m = __ballot(pass);
        if (pass) {
            int slot = (cnt + __popcll(m & lmask)) & 127;
            bq[w][slot] = q; bc[w][slot] = cdv;
        }
        cnt += __popcll(m);
        if (cnt - done >= 64) process(64);
    }
    if (cnt > done) process(cnt - done);

    for (int off = 32; off; off >>= 1) racc += __shfl_xor(racc, off);
    float bi = U1 / (racc + 1e-16f);

    unsigned long long ikey = (unsigned long long)(unsigned)(N - i);
    int np = min(npairs, PAIR_CAP);
    for (int t = lane; t < np; t += 64) {
        float v = sK[w][t] * bi;
        if (v > 0.f) {
            unsigned long long key = ((unsigned long long)__float_as_uint(v) << 32) | ikey;
            atomicMax(&colkey[sJ[w][t]], key);
        }
    }
}

// ---------------- decode colmax -> winner atomics; wave-aggregated flag atomics ----------------
__global__ void k_post(const unsigned long long* __restrict__ colkey,
                       const float* __restrict__ svp, const int* __restrict__ gt,
                       int* __restrict__ winnerHi, int* __restrict__ winnerLo,
                       int* __restrict__ flags) {
    int j = blockIdx.x * 256 + threadIdx.x;
    int lane = threadIdx.x & 63;
    bool valid = j < N;
    float vv = 0.f; int bidx = 0;
    if (valid) {
        unsigned long long key = colkey[j];
        bidx = key ? (N - (int)(key & 0xffffffffull)) : 0;
        vv = svp[bidx*OCH + gt[j]];
    }
    bool hi = valid && (vv > 0.1f);
    bool nothi = valid && !(vv > 0.1f);
    bool lo = valid && (vv > 0.0f);
    bool notlo = valid && !(vv > 0.0f);
    if (hi) atomicMax(&winnerHi[bidx], j);
    if (lo) atomicMax(&winnerLo[bidx], j);
    unsigned long long m0 = __ballot(hi);
    unsigned long long m1 = __ballot(nothi);
    unsigned long long m2 = __ballot(notlo);
    if (lane == 0) {
        if (m0) atomicOr(&flags[0], 1);
        if (m1) atomicOr(&flags[1], 1);
        if (m2) atomicOr(&flags[2], 1);
    }
}

// ---------------- merged outputs: blocks 0-7 rowsout, block 8 trust ----------------
__global__ void __launch_bounds__(1024) k_final(
    const int* __restrict__ winnerHi, const int* __restrict__ winnerLo,
    const int* __restrict__ flags, const int* __restrict__ gt,
    const float* __restrict__ svp,
    float* __restrict__ o_svp, float* __restrict__ o_pre,
    float* __restrict__ out0, float* __restrict__ out5) {
    int bx = blockIdx.x, tid = threadIdx.x;
    const int* winner = flags[0] ? winnerHi : winnerLo;
    if (bx < 8) {
        int i = bx*1024 + tid;
        if (i >= N) return;
        int w = winner[i];
        float row[OCH];
        if (w >= 0) {
            int g = gt[w];
            for (int c = 0; c < OCH; ++c) row[c] = (c == g) ? 1.f : 0.f;
        } else {
            for (int c = 0; c < OCH; ++c) row[c] = svp[i*OCH + c];
        }
        int p = 0; float m = row[0];
        for (int c = 0; c < OCH; ++c) {
            o_svp[i*OCH + c] = row[c];
            if (c > 0 && row[c] > m) { m = row[c]; p = c; }
        }
        o_pre[i] = (float)p;
    } else {
        __shared__ int wsum[16];
        int off = flags[0] ? (flags[1] ? 1 : 0) : (flags[2] ? 1 : 0);
        for (int p = tid; p < N; p += 1024) { out0[p] = -1.f; out5[p] = -1.f; }
        __syncthreads();
        int base = 0;
        for (int round = 0; round < N; round += 1024) {
            int i = round + tid;
            int pres = (i < N && winner[i] >= 0) ? 1 : 0;
            unsigned long long mask = __ballot(pres);
            int lane = tid & 63;
            int wv = tid >> 6;
            int excl = (lane == 0) ? 0 : __popcll(mask & (~0ull >> (64 - lane)));
            if (lane == 0) wsum[wv] = __popcll(mask);
            __syncthreads();
            int wpre = 0, tot = 0;
            for (int t = 0; t < 16; ++t) { if (t < wv) wpre += wsum[t]; tot += wsum[t]; }
            int pos = base + wpre + excl + off;
            if (pres && pos < N) { out0[pos] = (float)i; out5[pos] = (float)i; }
            base += tot;
            __syncthreads();
        }
    }
}

// ---------------- launch ----------------
extern "C" void kernel_launch(void* const* d_in, const int* in_sizes, int n_in,
                              void* d_out, int out_size, void* d_ws, size_t ws_size,
                              hipStream_t stream) {
    const float* sur_feat   = (const float*)d_in[0];
    const float* sur_coords = (const float*)d_in[1];
    const int*   sur_gt     = (const int*)d_in[2];
    const float* sv_prob    = (const float*)d_in[3];
    const float* mean_feat  = (const float*)d_in[4];
    const float* ori        = (const float*)d_in[5];
    const float* posses     = (const float*)d_in[6];

    float* out = (float*)d_out;
    float* o_trust  = out;
    float* o_mf     = out + 8000;
    float* o_ori    = out + 776000;
    float* o_pre    = out + 800000;
    float* o_svp    = out + 808000;
    float* o_trust2 = out + 960000;

    float* w = (float*)d_ws;
    float* w2 = w;                 w += N;        // 8000
    float4* alN = (float4*)w;      w += 4*N;      // 32000
    int* cellB = (int*)w;          w += N;        // 8000
    int* histB = (int*)w;          w += HSZ;      // 32000
    unsigned long long* colkey = (unsigned long long*)w;  w += 4*N;   // 16000 floats, 16B-aligned
    int* flags = (int*)w;          w += 8;
    int* csB = (int*)w;            w += 1008;
    float* svp = w;                w += N*OCH;    // 152000
    int* idBR = (int*)w;           w += N;
    float4* alR = (float4*)w;      w += 4*N;      // 32000
    int* winnerHi = (int*)w;       w += N;        // contiguous with winnerLo (int4-inited)
    int* winnerLo = (int*)w;       w += N;

    dim3 b256(256);

    hipMemsetAsync(histB, 0, (size_t)HSZ * 4, stream);

    k_prep<<<256, b256, 0, stream>>>(sur_feat, sur_coords, posses, sv_prob, mean_feat, ori,
                                     w2, alN, cellB, histB, svp, o_mf, o_ori,
                                     (float4*)colkey, (int4*)winnerHi, flags);
    k_scan<<<1, 1024, 0, stream>>>(histB, csB);
    k_scatter<<<32, b256, 0, stream>>>(cellB, histB, alN, idBR, alR);
    k_pairs<<<N/4, b256, 0, stream>>>((const float4*)mean_feat, ori, alR, w2,
                                      (const float4*)sur_feat, idBR, csB, colkey);
    k_post<<<32, b256, 0, stream>>>(colkey, svp, sur_gt, winnerHi, winnerLo, flags);
    k_final<<<9, 1024, 0, stream>>>(winnerHi, winnerLo, flags, sur_gt, svp,
                                    o_svp, o_pre, o_trust, o_trust2);
}